// Round 10
// baseline (285.092 us; speedup 1.0000x reference)
//
#include <hip/hip_runtime.h>

// TV denoiser (Chambolle-Pock), 40 iterations = 5 launches x 8 fused steps.
// Temporal blocking on an 80x80 staged region -> central 64x64 output.
//
// Round-10 layout: COLUMN STRIPS. Thread (s,lc) owns rows 10s..10s+9 of
// column lc (8 strips x 80 cols = 640 threads). Vertical neighbors (u0 above,
// w below) are REGISTERS; LDS only carries the horizontal exchange:
//   su1T[c][row] (transposed, stride 84): u1 of col c-1, read by col c
//   swT [c][row] (transposed, stride 84): w  of col c,  read by col c-1
// plus strip-boundary arrays u0Bot[s][lc], wTop[s][lc] (stride-1).
// Stride 84: lane-stride mod 32 = 20 -> b64 lane-groups tile all 32 banks
// (conflict-free); 84*4 B is 16B-aligned. Round-9's 819K conflicts came from
// stride-2 b32 reads; all reads here are lane-stride-1 or stride-84.
// -> 2.4 LDS instrs/cell/step (vs 3.5), ~26 VALU/cell (vs ~36).
//
// Masks identical to verified rounds 8/9: phase 1 unconditional (garbage w
// provably never reaches an active phase-2 cell; edge factors multiply only
// finite values); phase 2 uses t < tm selects so inactive/OOB cells stay
// exactly 0 (round-2 invariant). tm/ehf precomputed once into registers.
//
// __launch_bounds__(640,2): 2nd arg acts as blocks/CU (round-8/9 evidence)
// -> VGPR cap 102; live state ~95. LDS 59.9 KB -> 2 blocks/CU (20 waves).
//
// first=1: u==0, x2==y (skips loads; no memset). last=1: skip u stores.

#define Hh 512
#define Ww 512
#define Bb 8
#define TS 64
#define KF 8
#define S  80
#define NT 640
#define RS 10          // rows per strip
#define NS 8           // strips
#define ST 84          // row-dim stride of transposed cols

__global__ __launch_bounds__(NT, 2)
void tv_fused(const float*  __restrict__ x2_in,
              const float2* __restrict__ u_in,
              const float*  __restrict__ y_in,
              float*  __restrict__ x2_out,
              float2* __restrict__ u_out,
              int first, int last)
{
    constexpr float TAU = 0.01f;
    constexpr float RHO = 1.99f;
    constexpr float SIGMA = 12.5f;       // 1/TAU/8
    constexpr float THS = 0.1f;
    constexpr float INV_1PT = 1.0f / 1.01f;

    __shared__ float su1T[81 * ST];      // col c holds u1 of col c-1; col 0 = zeros
    __shared__ float swT [80 * ST];      // col c holds w of col c
    __shared__ float u0B [9 * 80];       // u0B[s][lc] = u0 at row 10s-1 (strip s-1 bottom); s=0 zeros
    __shared__ float wTop[9 * 80];       // wTop[s][lc] = w at row 10s (strip s top); s=8 zeros

    const int b   = blockIdx.z;
    const int r0  = blockIdx.y * TS;
    const int c0  = blockIdx.x * TS;
    const int tid = threadIdx.x;
    const size_t plane = (size_t)b * (Hh * Ww);

    const int s  = tid / 80;             // 0..7
    const int lc = tid - s * 80;         // 0..79
    const int gc = c0 - KF + lc;
    const bool colin = (gc >= 0) & (gc < Ww);
    const float ewf = (gc < Ww - 1) ? 1.f : 0.f;
    const int gr0 = r0 - KF + RS * s;    // global row of strip row 0
    const int lr0 = RS * s;

    // zero the boundary-condition regions (never written again)
    if (tid < ST)                    su1T[tid] = 0.f;            // col -1 u1
    else if (tid < ST + 80)          wTop[8 * 80 + tid - ST] = 0.f;
    else if (tid < ST + 160)         u0B [tid - ST - 80] = 0.f;  // row -1 u0

    float u0[RS], u1[RS], x2[RS], yv[RS], w[RS], ehf[RS];
    int   tm[RS];

    // ---- stage: global -> registers (+ u1/u0 boundary into LDS)
    #pragma unroll
    for (int i = 0; i < RS; ++i) {
        const int gr = gr0 + i;
        const int lr = lr0 + i;
        const bool img = colin & (gr >= 0) & (gr < Hh);
        float a = 0.f, c = 0.f, z0 = 0.f, z1 = 0.f;
        if (img) {
            size_t gi = plane + (size_t)gr * Ww + gc;
            c = y_in[gi];
            if (first) a = c;
            else {
                a = x2_in[gi];
                float2 uu = u_in[gi];
                z0 = uu.x; z1 = uu.y;
            }
        }
        u0[i] = z0; u1[i] = z1; x2[i] = a; yv[i] = c;
        ehf[i] = (gr < Hh - 1) ? 1.f : 0.f;
        tm[i] = img ? min(min(lr, S - 1 - lr), min(lc, S - 1 - lc)) : 0;
    }
    {
        const int wbase = (lc + 1) * ST + lr0;
        #pragma unroll
        for (int j = 0; j < RS / 2; ++j)
            *(float2*)&su1T[wbase + 2 * j] = make_float2(u1[2 * j], u1[2 * j + 1]);
        u0B[(s + 1) * 80 + lc] = u0[RS - 1];
    }
    __syncthreads();

    const int rdU = lc * ST + lr0;                       // u1-left read base
    const int rdW = ((lc == 79) ? 0 : lc + 1) * ST + lr0; // w-right read base (clamped; lc=79 never active)
    const int wrW = lc * ST + lr0;
    const int wrU = (lc + 1) * ST + lr0;

    for (int t = 0; t < KF; ++t) {
        // ---- phase 1: w = 2x - x2 (unconditional)
        float nb[RS];
        #pragma unroll
        for (int j = 0; j < RS / 2; ++j) {
            float2 v = *(const float2*)&su1T[rdU + 2 * j];
            nb[2 * j] = v.x; nb[2 * j + 1] = v.y;
        }
        float u0a = u0B[s * 80 + lc];
        #pragma unroll
        for (int i = 0; i < RS; ++i) {
            float ua = (i == 0) ? u0a : u0[i - 1];
            float adj = ua - u0[i] + nb[i] - u1[i];
            float xv = fmaf(TAU, yv[i] - adj, x2[i]);       // x*(1+TAU)
            w[i] = fmaf(2.0f * INV_1PT, xv, -x2[i]);        // 2x - x2
        }
        #pragma unroll
        for (int j = 0; j < RS / 2; ++j)
            *(float2*)&swT[wrW + 2 * j] = make_float2(w[2 * j], w[2 * j + 1]);
        wTop[s * 80 + lc] = w[0];
        __syncthreads();

        // ---- phase 2: u, x2 update (selects freeze inactive/OOB cells)
        #pragma unroll
        for (int j = 0; j < RS / 2; ++j) {
            float2 v = *(const float2*)&swT[rdW + 2 * j];
            nb[2 * j] = v.x; nb[2 * j + 1] = v.y;
        }
        float wbot = wTop[(s + 1) * 80 + lc];
        #pragma unroll
        for (int i = 0; i < RS; ++i) {
            float wb = (i == RS - 1) ? wbot : w[i + 1];
            float dh = ehf[i] * (wb - w[i]);
            float dw = ewf * (nb[i] - w[i]);
            float v0 = fmaf(SIGMA, dh, u0[i]);
            float v1 = fmaf(SIGMA, dw, u1[i]);
            float iv = fminf(THS * __builtin_amdgcn_rsqf(fmaf(v0, v0, v1 * v1)), 1.f);
            bool a = t < tm[i];
            u0[i] = a ? fmaf(RHO, v0 * iv - u0[i], u0[i]) : u0[i];
            u1[i] = a ? fmaf(RHO, v1 * iv - u1[i], u1[i]) : u1[i];
            x2[i] = a ? fmaf(0.5f * RHO, w[i] - x2[i], x2[i]) : x2[i];
        }
        #pragma unroll
        for (int j = 0; j < RS / 2; ++j)
            *(float2*)&su1T[wrU + 2 * j] = make_float2(u1[2 * j], u1[2 * j + 1]);
        u0B[(s + 1) * 80 + lc] = u0[RS - 1];
        __syncthreads();
    }

    // ---- store central 64x64 straight from registers
    if (lc >= KF && lc < KF + TS) {
        #pragma unroll
        for (int i = 0; i < RS; ++i) {
            const int lr = lr0 + i;
            if (lr >= KF && lr < KF + TS) {
                size_t gi = plane + (size_t)(gr0 + i) * Ww + gc;
                x2_out[gi] = x2[i];
                if (!last) u_out[gi] = make_float2(u0[i], u1[i]);
            }
        }
    }
}

extern "C" void kernel_launch(void* const* d_in, const int* in_sizes, int n_in,
                              void* d_out, int out_size, void* d_ws, size_t ws_size,
                              hipStream_t stream)
{
    const float* y = (const float*)d_in[0];
    float* out = (float*)d_out;
    const size_t NP = (size_t)Bb * Hh * Ww;   // 2M cells

    float*  ws  = (float*)d_ws;
    float*  x2A = ws;                          // 8 MB
    float*  x2B = ws + NP;                     // 8 MB
    float2* uA  = (float2*)(ws + 2 * NP);      // 16 MB
    float2* uB  = (float2*)(ws + 4 * NP);      // 16 MB
    // total ws use: 48 MB; no memset (first=1 treats u as 0, x2 as y)

    dim3 grid(Ww / TS, Hh / TS, Bb);   // 8 x 8 x 8 = 512 blocks

    tv_fused<<<grid, NT, 0, stream>>>(y,   uB, y, x2A, uA, 1, 0);
    tv_fused<<<grid, NT, 0, stream>>>(x2A, uA, y, x2B, uB, 0, 0);
    tv_fused<<<grid, NT, 0, stream>>>(x2B, uB, y, x2A, uA, 0, 0);
    tv_fused<<<grid, NT, 0, stream>>>(x2A, uA, y, x2B, uB, 0, 0);
    tv_fused<<<grid, NT, 0, stream>>>(x2B, uB, y, out, uA, 0, 1);
}

// Round 12
// 234.006 us; speedup vs baseline: 1.2183x; 1.2183x over previous
//
#include <hip/hip_runtime.h>

// TV denoiser (Chambolle-Pock), 40 iterations = 5 launches x 8 fused steps.
// Temporal blocking: 64x64 staged region -> central 48x48 output (KF=8).
//
// Round-12: wave = strip, cross-lane exchange via __shfl (VERIFIED wave-wide
// on gfx950; round-11's DPP wave_shl1/wave_shr1 silently mis-shifted at
// 16-lane row boundaries -> absmax 0.14 fail. Lesson: only __shfl /
// ds_permute / ds_swizzle are verified cross-lane mechanisms on CDNA4).
//
// 512 threads = 8 waves; wave s owns rows 8s..8s+7 of all 64 staged columns
// (thread = one column x 8 rows in REGISTERS). Vertical neighbors: registers.
// Horizontal neighbors: __shfl_up(u1,1) [phase 1] / __shfl_down(w,1) [phase 2].
// Lane-edge clamp garbage (lane 0 / lane 63 receive own value) is harmless:
// columns lc=0/63 have tm=0 (never active) and their w feeds only inactive
// cells (cone argument verified rounds 8-10). Strip boundaries cross waves
// via two tiny stride-1 LDS arrays u0B/wTop (4.6 KB, conflict-free).
//
// Masks: phase 1 unconditional; phase 2 t < tm selects freeze inactive/OOB
// cells exactly (round-2 invariant). Central output cells have tm >= KF.
// __launch_bounds__(512,2): 2nd arg acts as blocks/CU (rounds 8/9), VGPR cap
// 128, live state ~80 -> no spill (round-8 lesson: check WRITE_SIZE stays 24.5 MB).
// first=1: u==0, x2==y (no memset). last=1: skip u stores.

#define Hh 512
#define Ww 512
#define Bb 8
#define TS 48
#define KF 8
#define S  64
#define NT 512
#define RS 8           // rows per strip = rows per thread

__global__ __launch_bounds__(NT, 2)
void tv_fused(const float*  __restrict__ x2_in,
              const float2* __restrict__ u_in,
              const float*  __restrict__ y_in,
              float*  __restrict__ x2_out,
              float2* __restrict__ u_out,
              int first, int last)
{
    constexpr float TAU = 0.01f;
    constexpr float RHO = 1.99f;
    constexpr float SIGMA = 12.5f;       // 1/TAU/8
    constexpr float THS = 0.1f;
    constexpr float INV_1PT = 1.0f / 1.01f;

    __shared__ float u0B [9 * S];   // u0B[s][lc] = u0 of row 8s-1 (strip s-1 bottom); s=0 zeros
    __shared__ float wTop[9 * S];   // wTop[s][lc] = w of row 8s (strip s top); s=8 zeros

    const int b   = blockIdx.z;
    const int r0  = blockIdx.y * TS;
    const int c0  = blockIdx.x * TS;
    const int tid = threadIdx.x;
    const size_t plane = (size_t)b * (Hh * Ww);

    const int s   = tid >> 6;            // 0..7 == wave id
    const int lc  = tid & 63;            // 0..63 == lane id
    const int gc  = c0 - KF + lc;
    const bool colin = (gc >= 0) & (gc < Ww);
    const float ewf = (gc < Ww - 1) ? 1.f : 0.f;
    const int lr0 = RS * s;
    const int gr0 = r0 - KF + lr0;

    if (tid < S) { u0B[tid] = 0.f; wTop[8 * S + tid] = 0.f; }

    float u0[RS], u1[RS], x2[RS], yv[RS], w[RS], ehf[RS];
    int   tm[RS];

    // ---- stage: global -> registers
    #pragma unroll
    for (int i = 0; i < RS; ++i) {
        const int gr = gr0 + i;
        const int lr = lr0 + i;
        const bool img = colin & (gr >= 0) & (gr < Hh);
        float a = 0.f, c = 0.f, z0 = 0.f, z1 = 0.f;
        if (img) {
            size_t gi = plane + (size_t)gr * Ww + gc;
            c = y_in[gi];
            if (first) a = c;
            else {
                a = x2_in[gi];
                float2 uu = u_in[gi];
                z0 = uu.x; z1 = uu.y;
            }
        }
        u0[i] = z0; u1[i] = z1; x2[i] = a; yv[i] = c;
        ehf[i] = (gr < Hh - 1) ? 1.f : 0.f;
        tm[i] = img ? min(min(lr, S - 1 - lr), min(lc, S - 1 - lc)) : 0;
    }
    u0B[(s + 1) * S + lc] = u0[RS - 1];
    __syncthreads();

    for (int t = 0; t < KF; ++t) {
        // ---- phase 1: w = 2x - x2 (unconditional; garbage never escapes cone)
        {
            float u0a = u0B[s * S + lc];
            #pragma unroll
            for (int i = 0; i < RS; ++i) {
                float ul = __shfl_up(u1[i], 1, 64);      // u1 of col lc-1 (lane 0: own value; col 0 w feeds only inactive cells)
                float ua = (i == 0) ? u0a : u0[i - 1];
                float adj = ua - u0[i] + ul - u1[i];
                float xv = fmaf(TAU, yv[i] - adj, x2[i]);    // x*(1+TAU)
                w[i] = fmaf(2.0f * INV_1PT, xv, -x2[i]);     // 2x - x2
            }
            wTop[s * S + lc] = w[0];
        }
        __syncthreads();
        // ---- phase 2: u, x2 update (selects freeze inactive/OOB cells)
        {
            float wbot = wTop[(s + 1) * S + lc];
            #pragma unroll
            for (int i = 0; i < RS; ++i) {
                float wr = __shfl_down(w[i], 1, 64);     // w of col lc+1 (lane 63: own value; cell 63 inactive)
                float wb = (i == RS - 1) ? wbot : w[i + 1];
                float dh = ehf[i] * (wb - w[i]);
                float dw = ewf * (wr - w[i]);
                float v0 = fmaf(SIGMA, dh, u0[i]);
                float v1 = fmaf(SIGMA, dw, u1[i]);
                float iv = fminf(THS * __builtin_amdgcn_rsqf(fmaf(v0, v0, v1 * v1)), 1.f);
                bool a = t < tm[i];
                u0[i] = a ? fmaf(RHO, v0 * iv - u0[i], u0[i]) : u0[i];
                u1[i] = a ? fmaf(RHO, v1 * iv - u1[i], u1[i]) : u1[i];
                x2[i] = a ? fmaf(0.5f * RHO, w[i] - x2[i], x2[i]) : x2[i];
            }
            u0B[(s + 1) * S + lc] = u0[RS - 1];
        }
        __syncthreads();
    }

    // ---- store central 48x48 straight from registers
    if (s >= 1 && s <= 6 && lc >= KF && lc < KF + TS && gc < Ww) {
        #pragma unroll
        for (int i = 0; i < RS; ++i) {
            const int gr = gr0 + i;
            if (gr < Hh) {
                size_t gi = plane + (size_t)gr * Ww + gc;
                x2_out[gi] = x2[i];
                if (!last) u_out[gi] = make_float2(u0[i], u1[i]);
            }
        }
    }
}

extern "C" void kernel_launch(void* const* d_in, const int* in_sizes, int n_in,
                              void* d_out, int out_size, void* d_ws, size_t ws_size,
                              hipStream_t stream)
{
    const float* y = (const float*)d_in[0];
    float* out = (float*)d_out;
    const size_t NP = (size_t)Bb * Hh * Ww;   // 2M cells

    float*  ws  = (float*)d_ws;
    float*  x2A = ws;                          // 8 MB
    float*  x2B = ws + NP;                     // 8 MB
    float2* uA  = (float2*)(ws + 2 * NP);      // 16 MB
    float2* uB  = (float2*)(ws + 4 * NP);      // 16 MB
    // total ws use: 48 MB; no memset (first=1 treats u as 0, x2 as y)

    dim3 grid((Ww + TS - 1) / TS, (Hh + TS - 1) / TS, Bb);   // 11 x 11 x 8 = 968 blocks

    tv_fused<<<grid, NT, 0, stream>>>(y,   uB, y, x2A, uA, 1, 0);
    tv_fused<<<grid, NT, 0, stream>>>(x2A, uA, y, x2B, uB, 0, 0);
    tv_fused<<<grid, NT, 0, stream>>>(x2B, uB, y, x2A, uA, 0, 0);
    tv_fused<<<grid, NT, 0, stream>>>(x2A, uA, y, x2B, uB, 0, 0);
    tv_fused<<<grid, NT, 0, stream>>>(x2B, uB, y, out, uA, 0, 1);
}